// Round 9
// baseline (8494.691 us; speedup 1.0000x reference)
//
#include <hip/hip_runtime.h>

// ---------------------------------------------------------------------------
// 2-layer LSTM, T=1024, B=32, D=256, H=512. Inputs fp32, OUTPUT fp32.
//   pack_w3: fp32 {W_hh0, W_hh1, W_ih1} -> bf16 MFMA B-fragment order.
//   gemm_xp: xp0 = x @ W_ih0^T (bf16 MFMA).
//   lstm_fused: persistent 64-wg x 256-thr kernel (R7 shape). wgs 0..31 =
//     layer0, 32..63 = layer1 (lag 1 step). NO FLAGS, NO DRAINS: every step
//     has a write-once slot (hs0[t], h1buf[t]) pre-poisoned to bf16 NaN
//     (0xFF bytes); consumers poll staged dwords until != 0xFFFFFFFF.
//     Data-as-signal cuts the per-step chain from ~3.5 MALL RTTs (store ack +
//     flag store + propagate + poll + load) to ~1.5 (store -> poll-load).
// ---------------------------------------------------------------------------

typedef __bf16 bf16x8 __attribute__((ext_vector_type(8)));
typedef float  f32x4  __attribute__((ext_vector_type(4)));
typedef float  f32x2  __attribute__((ext_vector_type(2)));
typedef unsigned long long u64;
typedef unsigned int u32;

#define MFMA16(a, b, c) __builtin_amdgcn_mfma_f32_16x16x32_bf16((a), (b), (c), 0, 0, 0)
#define SCOPE_AGENT __HIP_MEMORY_SCOPE_AGENT

__device__ __forceinline__ float fsigm(float x) { return 1.0f / (1.0f + __expf(-x)); }
__device__ __forceinline__ float ftanh(float x) {
    x = fminf(15.0f, fmaxf(-15.0f, x));
    float e = __expf(2.0f * x);
    return (e - 1.0f) / (e + 1.0f);
}

__device__ __forceinline__ bf16x8 frag_from(u64 lo, u64 hi) {
    union { u64 u[2]; bf16x8 v; } x;
    x.u[0] = lo; x.u[1] = hi;
    return x.v;
}

__device__ __forceinline__ bool slot_valid(u64 x) {
    // poisoned dword = 0xFFFFFFFF (two bf16 NaNs); h is never NaN.
    return ((u32)x != 0xFFFFFFFFu) && ((u32)(x >> 32) != 0xFFFFFFFFu);
}

// ---------------------------------------------------------------------------
// Pack [2048][512] fp32 -> per-(wg,wave,ktile) bf16 B-fragment order:
//   WB[((w*4+v)*16+kk)*512 + lane*8 + e] = bf16(W[grow][k0+e])
//   n = v*16+(lane&15); grow = (n>>4)*512 + w*16 + (n&15); k0 = kk*32+(lane>>4)*8
// ---------------------------------------------------------------------------
__global__ void pack_w3(const float* __restrict__ W0, const float* __restrict__ W1,
                        const float* __restrict__ W2, __bf16* __restrict__ O0,
                        __bf16* __restrict__ O1, __bf16* __restrict__ O2) {
    int gtid = blockIdx.x * 256 + threadIdx.x;          // 0 .. 393215
    int sel  = gtid >> 17;                              // 0,1,2
    const float* W = (sel == 0) ? W0 : (sel == 1) ? W1 : W2;
    __bf16* WB     = (sel == 0) ? O0 : (sel == 1) ? O1 : O2;
    int tid  = gtid & 131071;
    int lane = tid & 63;
    int kk   = (tid >> 6) & 15;
    int v    = (tid >> 10) & 3;
    int w    = tid >> 12;                               // 0..31
    int n    = v * 16 + (lane & 15);
    int grow = (n >> 4) * 512 + w * 16 + (n & 15);
    int k0   = kk * 32 + (lane >> 4) * 8;
    const float* src = W + (size_t)grow * 512 + k0;
    bf16x8 val;
#pragma unroll
    for (int e = 0; e < 8; e++) val[e] = (__bf16)src[e];
    *(bf16x8*)(WB + (size_t)tid * 8) = val;
}

// ---------------------------------------------------------------------------
// xp0[r][n] = sum_k x_perm(r)[k] * W[n][k], r = t*32+b, x is [B,T,D] fp32.
// ---------------------------------------------------------------------------
__global__ __launch_bounds__(256, 2) void gemm_xp(const float* __restrict__ A,
                                                  const float* __restrict__ W,
                                                  __bf16* __restrict__ out, int K) {
    const int tid = threadIdx.x, lane = tid & 63, wv = tid >> 6;
    const int bm = blockIdx.x >> 4, bn = blockIdx.x & 15;
    const int m_base = bm * 128 + (wv & 1) * 64;
    const int n_base = bn * 128 + (wv >> 1) * 64;
    const int kq = (lane >> 4) * 8;
    const int rl = lane & 15;

    f32x4 acc[4][4];
#pragma unroll
    for (int i = 0; i < 4; i++)
#pragma unroll
        for (int j = 0; j < 4; j++) acc[i][j] = (f32x4){0.f, 0.f, 0.f, 0.f};

    const int nk = K >> 5;
    for (int kk = 0; kk < nk; kk++) {
        int k0 = kk * 32 + kq;
        bf16x8 af[4], bfr[4];
#pragma unroll
        for (int mt = 0; mt < 4; mt++) {
            int row = m_base + mt * 16 + rl;
            const float* ap = A + (size_t)((row & 31) * 1024 + (row >> 5)) * K + k0;
#pragma unroll
            for (int e = 0; e < 8; e++) af[mt][e] = (__bf16)ap[e];
        }
#pragma unroll
        for (int nt = 0; nt < 4; nt++) {
            int n = n_base + nt * 16 + rl;
            const float* wp = W + (size_t)n * K + k0;
#pragma unroll
            for (int e = 0; e < 8; e++) bfr[nt][e] = (__bf16)wp[e];
        }
#pragma unroll
        for (int mt = 0; mt < 4; mt++)
#pragma unroll
            for (int nt = 0; nt < 4; nt++)
                acc[mt][nt] = MFMA16(af[mt], bfr[nt], acc[mt][nt]);
    }

    const int rq = (lane >> 4) * 4;
#pragma unroll
    for (int mt = 0; mt < 4; mt++)
#pragma unroll
        for (int nt = 0; nt < 4; nt++)
#pragma unroll
            for (int r = 0; r < 4; r++) {
                int row = m_base + mt * 16 + rq + r;
                int col = n_base + nt * 16 + rl;
                out[(size_t)row * 2048 + col] = (__bf16)acc[mt][nt][r];
            }
}

// ---------------------------------------------------------------------------
// Fused pipelined recurrence, data-as-signal. 64 wgs x 256. wg<32: layer0
// (w=wg); wg>=32: layer1 (w=wg-32). wg owns h-cols w*16..+16 for all 4 gates.
// Layer0 step t: stages hs0[t-1] (NaN-poll), 32 MFMAs, stores hs0[t] (atomic).
// Layer1 step t: stages h1buf[t-1] + hs0[t] (NaN-poll), 64 MFMAs, stores
// h1buf[t] + out row t. Write-once slots -> no WAR guard, no flags, no drains.
// ---------------------------------------------------------------------------
__global__ __launch_bounds__(256, 1) void lstm_fused(
    const __bf16* __restrict__ xp0,   // [32768][2048] bf16, row = t*32+b
    const __bf16* __restrict__ WB0,   // W_hh0 packed
    const __bf16* __restrict__ WB1,   // W_hh1 packed
    const __bf16* __restrict__ WBi1,  // W_ih1 packed
    const float* __restrict__ bias0,
    const float* __restrict__ bias1,
    __bf16* __restrict__ hs0_bf,      // [1024][32][512], NaN-poisoned
    __bf16* __restrict__ h1buf,       // [1024][32][512], NaN-poisoned
    float* __restrict__ out_f32,      // [32][1024][512]
    float* __restrict__ hn_out,       // [2][32][512]
    float* __restrict__ cn_out) {     // [2][32][512]
    const int tid   = threadIdx.x;
    const int wg    = blockIdx.x;   // 0..63
    const int layer = wg >> 5;
    const int w     = wg & 31;
    const int lane  = tid & 63;
    const int wv    = tid >> 6;

    __shared__ __bf16 h_lds[32 * 516];  // own-state mirror (stride 516)
    __shared__ __bf16 s_lds[32 * 516];  // hs0[t] mirror (layer1)
    __shared__ float  g_lds[32 * 68];   // gates [32 b][64 cols +4]

    // --- weights resident in registers ---
    bf16x8 wregA[16], wregB[16];
    {
        const size_t wo = (size_t)(w * 4 + wv) * 16 * 512 + lane * 8;
        const __bf16* wa = (layer ? WB1 : WB0) + wo;
#pragma unroll
        for (int kk = 0; kk < 16; kk++) wregA[kk] = *(const bf16x8*)(wa + kk * 512);
        if (layer) {
            const __bf16* wb = WBi1 + wo;
#pragma unroll
            for (int kk = 0; kk < 16; kk++) wregB[kk] = *(const bf16x8*)(wb + kk * 512);
        }
    }

    const float* bias = layer ? bias1 : bias0;
    __bf16* mybuf = layer ? h1buf : hs0_bf;   // own-state history

    // --- elementwise mapping: thread -> (b, j0, j0+1) ---
    const int b  = tid >> 3;
    const int jp = tid & 7;
    const int j0 = w * 16 + jp * 2;
    f32x2 bsv[4];
#pragma unroll
    for (int g = 0; g < 4; g++) bsv[g] = *(const f32x2*)(bias + g * 512 + j0);
    float cc0 = 0.f, cc1 = 0.f;

    const int arow = lane & 15;
    const int kq8  = (lane >> 4) * 8;

    // xp prefetch (layer0 only)
    u32 xc[4] = {0, 0, 0, 0}, xn[4] = {0, 0, 0, 0};
    if (!layer) {
#pragma unroll
        for (int g = 0; g < 4; g++)
            xc[g] = *(const u32*)(xp0 + (size_t)b * 2048 + g * 512 + j0);
    }

    for (int t = 0; t < 1024; t++) {
        if (!layer) {
            int tn = (t < 1023) ? t + 1 : 1023;
#pragma unroll
            for (int g = 0; g < 4; g++)
                xn[g] = *(const u32*)(xp0 + (size_t)(tn * 32 + b) * 2048 + g * 512 + j0);
        }

        // --- stage own state h[t-1] (t>0) and, for layer1, hs0[t]:
        //     batched atomic loads + NaN-validity retry sweeps ---
        u64 hv[16], sv[16];
        if (t > 0) {
            const u64* hg = (const u64*)(mybuf + (size_t)(t - 1) * 16384);
#pragma unroll
            for (int i = 0; i < 16; i++)
                hv[i] = __hip_atomic_load(hg + i * 256 + tid, __ATOMIC_RELAXED, SCOPE_AGENT);
        }
        if (layer) {
            const u64* sg = (const u64*)(hs0_bf + (size_t)t * 16384);
#pragma unroll
            for (int i = 0; i < 16; i++)
                sv[i] = __hip_atomic_load(sg + i * 256 + tid, __ATOMIC_RELAXED, SCOPE_AGENT);
        }
        {
            u32 badh = 0, bads = 0;
            if (t > 0) {
#pragma unroll
                for (int i = 0; i < 16; i++)
                    badh |= (u32)(!slot_valid(hv[i])) << i;
            }
            if (layer) {
#pragma unroll
                for (int i = 0; i < 16; i++)
                    bads |= (u32)(!slot_valid(sv[i])) << i;
            }
            while (badh | bads) {
                __builtin_amdgcn_s_sleep(1);
                if (badh) {
                    const u64* hg = (const u64*)(mybuf + (size_t)(t - 1) * 16384);
#pragma unroll
                    for (int i = 0; i < 16; i++)
                        if (badh & (1u << i)) {
                            hv[i] = __hip_atomic_load(hg + i * 256 + tid,
                                                      __ATOMIC_RELAXED, SCOPE_AGENT);
                            if (slot_valid(hv[i])) badh &= ~(1u << i);
                        }
                }
                if (bads) {
                    const u64* sg = (const u64*)(hs0_bf + (size_t)t * 16384);
#pragma unroll
                    for (int i = 0; i < 16; i++)
                        if (bads & (1u << i)) {
                            sv[i] = __hip_atomic_load(sg + i * 256 + tid,
                                                      __ATOMIC_RELAXED, SCOPE_AGENT);
                            if (slot_valid(sv[i])) bads &= ~(1u << i);
                        }
                }
            }
        }
        if (t > 0) {
#pragma unroll
            for (int i = 0; i < 16; i++) {
                int f  = (i * 256 + tid) * 4;
                int br = f >> 9, col = f & 511;
                *(u64*)(h_lds + br * 516 + col) = hv[i];
            }
        }
        if (layer) {
#pragma unroll
            for (int i = 0; i < 16; i++) {
                int f  = (i * 256 + tid) * 4;
                int br = f >> 9, col = f & 511;
                *(u64*)(s_lds + br * 516 + col) = sv[i];
            }
        }
        __syncthreads();

        // --- MFMA: gates[b][gatecol] = h @ Whh^T (+ hs0 @ Wih1^T) ---
        f32x4 acc0 = (f32x4){0.f, 0.f, 0.f, 0.f};
        f32x4 acc1 = (f32x4){0.f, 0.f, 0.f, 0.f};
        if (t > 0) {
#pragma unroll
            for (int kk = 0; kk < 16; kk++) {
                const __bf16* p0 = h_lds + arow * 516 + kq8 + kk * 32;
                const __bf16* p1 = p0 + 16 * 516;
                bf16x8 a0 = frag_from(*(const u64*)p0, *(const u64*)(p0 + 4));
                bf16x8 a1 = frag_from(*(const u64*)p1, *(const u64*)(p1 + 4));
                acc0 = MFMA16(a0, wregA[kk], acc0);
                acc1 = MFMA16(a1, wregA[kk], acc1);
            }
        }
        if (layer) {
#pragma unroll
            for (int kk = 0; kk < 16; kk++) {
                const __bf16* p0 = s_lds + arow * 516 + kq8 + kk * 32;
                const __bf16* p1 = p0 + 16 * 516;
                bf16x8 a0 = frag_from(*(const u64*)p0, *(const u64*)(p0 + 4));
                bf16x8 a1 = frag_from(*(const u64*)p1, *(const u64*)(p1 + 4));
                acc0 = MFMA16(a0, wregB[kk], acc0);
                acc1 = MFMA16(a1, wregB[kk], acc1);
            }
        }
        {
            int col   = wv * 16 + (lane & 15);
            int rbase = (lane >> 4) * 4;
#pragma unroll
            for (int r = 0; r < 4; r++) {
                g_lds[(rbase + r) * 68 + col]      = acc0[r];
                g_lds[(16 + rbase + r) * 68 + col] = acc1[r];
            }
        }
        __syncthreads();

        // --- gate math: thread owns (b, j0, j0+1) ---
        float hf0, hf1;
        {
            union { u32 u; __bf16 v2[2]; } xi, xf, xg, xo;
            xi.u = xc[0]; xf.u = xc[1]; xg.u = xc[2]; xo.u = xc[3];
            const float* gl = g_lds + b * 68 + jp * 2;
            f32x2 gi = *(const f32x2*)(gl);
            f32x2 gf = *(const f32x2*)(gl + 16);
            f32x2 gg = *(const f32x2*)(gl + 32);
            f32x2 go = *(const f32x2*)(gl + 48);

            float i0 = fsigm(gi[0] + (float)xi.v2[0] + bsv[0][0]);
            float f0 = fsigm(gf[0] + (float)xf.v2[0] + bsv[1][0]);
            float g0 = ftanh(gg[0] + (float)xg.v2[0] + bsv[2][0]);
            float o0 = fsigm(go[0] + (float)xo.v2[0] + bsv[3][0]);
            cc0 = f0 * cc0 + i0 * g0;
            hf0 = o0 * ftanh(cc0);

            float i1 = fsigm(gi[1] + (float)xi.v2[1] + bsv[0][1]);
            float f1 = fsigm(gf[1] + (float)xf.v2[1] + bsv[1][1]);
            float g1 = ftanh(gg[1] + (float)xg.v2[1] + bsv[2][1]);
            float o1 = fsigm(go[1] + (float)xo.v2[1] + bsv[3][1]);
            cc1 = f1 * cc1 + i1 * g1;
            hf1 = o1 * ftanh(cc1);
        }
        union { __bf16 v2[2]; u32 u; } hu;
        hu.v2[0] = (__bf16)hf0; hu.v2[1] = (__bf16)hf1;

        // --- store h[t] into its write-once slot: this IS the signal ---
        if (!layer) {
            __hip_atomic_store((u32*)(hs0_bf + ((size_t)t * 32 + b) * 512 + j0), hu.u,
                               __ATOMIC_RELAXED, SCOPE_AGENT);
        } else {
            if (t < 1023)
                __hip_atomic_store((u32*)(h1buf + ((size_t)t * 32 + b) * 512 + j0), hu.u,
                                   __ATOMIC_RELAXED, SCOPE_AGENT);
            f32x2 hf2 = (f32x2){hf0, hf1};
            *(f32x2*)(out_f32 + (size_t)b * 524288 + (size_t)t * 512 + j0) = hf2;
        }
        if (t == 1023) {
            float* hn = hn_out + (size_t)layer * 16384;
            float* cn = cn_out + (size_t)layer * 16384;
            *(f32x2*)(hn + (size_t)b * 512 + j0) = (f32x2){hf0, hf1};
            *(f32x2*)(cn + (size_t)b * 512 + j0) = (f32x2){cc0, cc1};
        }
#pragma unroll
        for (int g = 0; g < 4; g++) xc[g] = xn[g];
    }
}

// ---------------------------------------------------------------------------
extern "C" void kernel_launch(void* const* d_in, const int* in_sizes, int n_in,
                              void* d_out, int out_size, void* d_ws, size_t ws_size,
                              hipStream_t stream) {
    (void)in_sizes; (void)n_in; (void)out_size; (void)ws_size;
    const float* x    = (const float*)d_in[0];  // [32][1024][256] fp32
    const float* Wih0 = (const float*)d_in[1];  // [2048][256] fp32
    const float* b0   = (const float*)d_in[2];  // [2048] fp32
    const float* Whh0 = (const float*)d_in[3];  // [2048][512] fp32
    const float* Wih1 = (const float*)d_in[4];  // [2048][512] fp32
    const float* b1   = (const float*)d_in[5];  // [2048] fp32
    const float* Whh1 = (const float*)d_in[6];  // [2048][512] fp32
    float* dout = (float*)d_out;  // fp32: out(16777216) | h_n(2*16384) | c_n(2*16384)

    char* wsb = (char*)d_ws;
    __bf16* WB0   = (__bf16*)wsb;                         // 2 MB
    __bf16* WB1   = (__bf16*)(wsb + (2 << 20));           // 2 MB
    __bf16* WBi1  = (__bf16*)(wsb + (4 << 20));           // 2 MB
    __bf16* hs0   = (__bf16*)(wsb + (6 << 20));           // 32 MB (per-t slots)
    __bf16* h1buf = (__bf16*)(wsb + (38 << 20));          // 32 MB (per-t slots)
    __bf16* xpb   = (__bf16*)(wsb + (70 << 20));          // 128 MB

    // poison hs0 + h1buf to bf16 NaN (0xFF bytes): the validity sentinel
    (void)hipMemsetAsync(wsb + (6 << 20), 0xFF, 64 << 20, stream);

    pack_w3<<<dim3(1536), dim3(256), 0, stream>>>(Whh0, Whh1, Wih1, WB0, WB1, WBi1);

    // xp0 = x @ Wih0^T  (K=256, fp32 A, permuted rows)
    gemm_xp<<<dim3(4096), dim3(256), 0, stream>>>(x, Wih0, xpb, 256);

    lstm_fused<<<dim3(64), dim3(256), 0, stream>>>(
        xpb, WB0, WB1, WBi1, b0, b1, hs0, h1buf,
        dout, dout + 16777216, dout + 16777216 + 32768);
}

// Round 10
// 3881.433 us; speedup vs baseline: 2.1885x; 2.1885x over previous
//
#include <hip/hip_runtime.h>

// ---------------------------------------------------------------------------
// 2-layer LSTM, T=1024, B=32, D=256, H=512. Inputs fp32, OUTPUT fp32.
//   pack_w3: fp32 {W_hh0, W_hh1, W_ih1} -> bf16 MFMA B-fragment order.
//   gemm_xp: xp0 = x @ W_ih0^T (bf16 MFMA).
//   lstm_pipe3: persistent 96-wg x 256-thr kernel, 3 stages of 32 wgs:
//     role0 L0 : layer0 recurrence (R6-shape loop, fan-in-32 flag barrier),
//                writes hs0[t] slots (write-once) + own double buffer.
//     role1 XP1: stateless xp1[t] = hs0[t] @ Wih1^T. NO self-sync (batch rows
//                independent). Ring depth 4, backpressure on L1[t-4].
//     role2 L1 : layer1 recurrence, loop identical to L0 (32 MFMAs, one
//                staging) + fan-in-1 poll of its matching XP1 wg + 4 direct
//                xp word loads (no LDS staging for xp1).
//   All exchange via proven fence-free relaxed agent atomics (R5/R6).
// ---------------------------------------------------------------------------

typedef __bf16 bf16x8 __attribute__((ext_vector_type(8)));
typedef float  f32x4  __attribute__((ext_vector_type(4)));
typedef float  f32x2  __attribute__((ext_vector_type(2)));
typedef unsigned long long u64;
typedef unsigned int u32;

#define MFMA16(a, b, c) __builtin_amdgcn_mfma_f32_16x16x32_bf16((a), (b), (c), 0, 0, 0)
#define SCOPE_AGENT __HIP_MEMORY_SCOPE_AGENT

__device__ __forceinline__ float fsigm(float x) { return 1.0f / (1.0f + __expf(-x)); }
__device__ __forceinline__ float ftanh(float x) {
    x = fminf(15.0f, fmaxf(-15.0f, x));
    float e = __expf(2.0f * x);
    return (e - 1.0f) / (e + 1.0f);
}

__device__ __forceinline__ bf16x8 frag_from(u64 lo, u64 hi) {
    union { u64 u[2]; bf16x8 v; } x;
    x.u[0] = lo; x.u[1] = hi;
    return x.v;
}

// ---------------------------------------------------------------------------
// Pack [2048][512] fp32 -> per-(wg,wave,ktile) bf16 B-fragment order:
//   WB[((w*4+v)*16+kk)*512 + lane*8 + e] = bf16(W[grow][k0+e])
//   n = v*16+(lane&15); grow = (n>>4)*512 + w*16 + (n&15); k0 = kk*32+(lane>>4)*8
// wg w owns h-cols [w*16, w*16+16) for all 4 gates.
// ---------------------------------------------------------------------------
__global__ void pack_w3(const float* __restrict__ W0, const float* __restrict__ W1,
                        const float* __restrict__ W2, __bf16* __restrict__ O0,
                        __bf16* __restrict__ O1, __bf16* __restrict__ O2) {
    int gtid = blockIdx.x * 256 + threadIdx.x;          // 0 .. 393215
    int sel  = gtid >> 17;                              // 0,1,2
    const float* W = (sel == 0) ? W0 : (sel == 1) ? W1 : W2;
    __bf16* WB     = (sel == 0) ? O0 : (sel == 1) ? O1 : O2;
    int tid  = gtid & 131071;
    int lane = tid & 63;
    int kk   = (tid >> 6) & 15;
    int v    = (tid >> 10) & 3;
    int w    = tid >> 12;                               // 0..31
    int n    = v * 16 + (lane & 15);
    int grow = (n >> 4) * 512 + w * 16 + (n & 15);
    int k0   = kk * 32 + (lane >> 4) * 8;
    const float* src = W + (size_t)grow * 512 + k0;
    bf16x8 val;
#pragma unroll
    for (int e = 0; e < 8; e++) val[e] = (__bf16)src[e];
    *(bf16x8*)(WB + (size_t)tid * 8) = val;
}

// ---------------------------------------------------------------------------
// xp0[r][n] = sum_k x_perm(r)[k] * W[n][k], r = t*32+b, x is [B,T,D] fp32.
// ---------------------------------------------------------------------------
__global__ __launch_bounds__(256, 2) void gemm_xp(const float* __restrict__ A,
                                                  const float* __restrict__ W,
                                                  __bf16* __restrict__ out, int K) {
    const int tid = threadIdx.x, lane = tid & 63, wv = tid >> 6;
    const int bm = blockIdx.x >> 4, bn = blockIdx.x & 15;
    const int m_base = bm * 128 + (wv & 1) * 64;
    const int n_base = bn * 128 + (wv >> 1) * 64;
    const int kq = (lane >> 4) * 8;
    const int rl = lane & 15;

    f32x4 acc[4][4];
#pragma unroll
    for (int i = 0; i < 4; i++)
#pragma unroll
        for (int j = 0; j < 4; j++) acc[i][j] = (f32x4){0.f, 0.f, 0.f, 0.f};

    const int nk = K >> 5;
    for (int kk = 0; kk < nk; kk++) {
        int k0 = kk * 32 + kq;
        bf16x8 af[4], bfr[4];
#pragma unroll
        for (int mt = 0; mt < 4; mt++) {
            int row = m_base + mt * 16 + rl;
            const float* ap = A + (size_t)((row & 31) * 1024 + (row >> 5)) * K + k0;
#pragma unroll
            for (int e = 0; e < 8; e++) af[mt][e] = (__bf16)ap[e];
        }
#pragma unroll
        for (int nt = 0; nt < 4; nt++) {
            int n = n_base + nt * 16 + rl;
            const float* wp = W + (size_t)n * K + k0;
#pragma unroll
            for (int e = 0; e < 8; e++) bfr[nt][e] = (__bf16)wp[e];
        }
#pragma unroll
        for (int mt = 0; mt < 4; mt++)
#pragma unroll
            for (int nt = 0; nt < 4; nt++)
                acc[mt][nt] = MFMA16(af[mt], bfr[nt], acc[mt][nt]);
    }

    const int rq = (lane >> 4) * 4;
#pragma unroll
    for (int mt = 0; mt < 4; mt++)
#pragma unroll
        for (int nt = 0; nt < 4; nt++)
#pragma unroll
            for (int r = 0; r < 4; r++) {
                int row = m_base + mt * 16 + rq + r;
                int col = n_base + nt * 16 + rl;
                out[(size_t)row * 2048 + col] = (__bf16)acc[mt][nt][r];
            }
}

// ---------------------------------------------------------------------------
// 3-stage pipelined recurrence. 96 wgs x 256. role = blockIdx/32, w = %32.
// wg w (any role) owns h-cols [w*16, w*16+16) x 4 gates.
// ---------------------------------------------------------------------------
__global__ __launch_bounds__(256, 1) void lstm_pipe3(
    const __bf16* __restrict__ xp0,    // [32768][2048] bf16, row = t*32+b
    const __bf16* __restrict__ WB0,    // W_hh0 packed
    const __bf16* __restrict__ WBw1,   // W_hh1 packed
    const __bf16* __restrict__ WBi1,   // W_ih1 packed
    const float* __restrict__ bias0,
    const float* __restrict__ bias1,
    __bf16* __restrict__ hbuf0,        // [2][32][512] zeroed
    __bf16* __restrict__ hbuf1,        // [2][32][512] zeroed
    __bf16* __restrict__ hs0s,         // [1024][32][512] write-once slots
    __bf16* __restrict__ xp1r,         // [4][32][2048] ring
    float* __restrict__ out_f32,       // [32][1024][512]
    float* __restrict__ hn_out,        // [2][32][512]
    float* __restrict__ cn_out,        // [2][32][512]
    int* __restrict__ fL0,             // [32][1024] zeroed, stride 1024
    int* __restrict__ fX,              // [32][1024] zeroed
    int* __restrict__ fL1) {           // [32][1024] zeroed
    const int tid  = threadIdx.x;
    const int role = blockIdx.x >> 5;   // 0=L0, 1=XP1, 2=L1
    const int w    = blockIdx.x & 31;
    const int lane = tid & 63;
    const int wv   = tid >> 6;

    __shared__ __bf16 h_lds[32 * 516];  // staged state (stride 516)
    __shared__ float  g_lds[32 * 68];   // gates [32 b][64 cols +4]

    // --- weights resident in registers (64 VGPRs/lane) ---
    bf16x8 wreg[16];
    {
        const __bf16* WB = (role == 0) ? WB0 : (role == 1) ? WBi1 : WBw1;
        const __bf16* wb = WB + (size_t)(w * 4 + wv) * 16 * 512 + lane * 8;
#pragma unroll
        for (int kk = 0; kk < 16; kk++) wreg[kk] = *(const bf16x8*)(wb + kk * 512);
    }

    // --- elementwise mapping: thread -> (b, j0, j0+1) ---
    const int b  = tid >> 3;
    const int jp = tid & 7;
    const int j0 = w * 16 + jp * 2;
    const int arow = lane & 15;
    const int kq8  = (lane >> 4) * 8;

    f32x2 bsv[4];
    if (role != 1) {
        const float* bias = (role == 0) ? bias0 : bias1;
#pragma unroll
        for (int g = 0; g < 4; g++) bsv[g] = *(const f32x2*)(bias + g * 512 + j0);
    }
    float cc0 = 0.f, cc1 = 0.f;

    __bf16* hbuf = (role == 0) ? hbuf0 : hbuf1;   // recurrent double buffer
    int* fMy = (role == 0) ? fL0 : (role == 1) ? fX : fL1;

    // xp0 prefetch (role 0 only)
    u32 xc[4] = {0, 0, 0, 0}, xn[4] = {0, 0, 0, 0};
    if (role == 0) {
#pragma unroll
        for (int g = 0; g < 4; g++)
            xc[g] = *(const u32*)(xp0 + (size_t)b * 2048 + g * 512 + j0);
    }

    for (int t = 0; t < 1024; t++) {
        // ---------------- top-of-step wait ----------------
        if (role == 0) {
            int tn = (t < 1023) ? t + 1 : 1023;
#pragma unroll
            for (int g = 0; g < 4; g++)
                xn[g] = *(const u32*)(xp0 + (size_t)(tn * 32 + b) * 2048 + g * 512 + j0);
            if (t > 0) {
                if (tid < 32)
                    while (__hip_atomic_load(&fL0[tid * 1024 + t - 1], __ATOMIC_RELAXED,
                                             SCOPE_AGENT) == 0) {}
                asm volatile("" ::: "memory");
                __syncthreads();
            }
        } else if (role == 1) {
            if (tid < 32)
                while (__hip_atomic_load(&fL0[tid * 1024 + t], __ATOMIC_RELAXED,
                                         SCOPE_AGENT) == 0) {}
            else if (tid == 32 && t >= 4)
                while (__hip_atomic_load(&fL1[w * 1024 + t - 4], __ATOMIC_RELAXED,
                                         SCOPE_AGENT) == 0) {}
            asm volatile("" ::: "memory");
            __syncthreads();
        } else {
            if (tid < 32) {
                if (t > 0)
                    while (__hip_atomic_load(&fL1[tid * 1024 + t - 1], __ATOMIC_RELAXED,
                                             SCOPE_AGENT) == 0) {}
            } else if (tid == 32) {
                while (__hip_atomic_load(&fX[w * 1024 + t], __ATOMIC_RELAXED,
                                         SCOPE_AGENT) == 0) {}
            }
            asm volatile("" ::: "memory");
            __syncthreads();
        }

        // ---------------- stage state into LDS ----------------
        // role0: hbuf0[t&1]; role1: hs0s[t]; role2: xp words + hbuf1[t&1]
        u32 xpr[4];
        if (role == 2) {
            const __bf16* xs = xp1r + (size_t)(t & 3) * 65536 + (size_t)b * 2048 + j0;
#pragma unroll
            for (int g = 0; g < 4; g++)
                xpr[g] = __hip_atomic_load((const u32*)(xs + g * 512),
                                           __ATOMIC_RELAXED, SCOPE_AGENT);
        }
        {
            const u64* hg = (role == 1)
                ? (const u64*)(hs0s + (size_t)t * 16384)
                : (const u64*)(hbuf + (size_t)(t & 1) * 16384);
            u64 hv[16];
#pragma unroll
            for (int i = 0; i < 16; i++)
                hv[i] = __hip_atomic_load(hg + i * 256 + tid, __ATOMIC_RELAXED, SCOPE_AGENT);
#pragma unroll
            for (int i = 0; i < 16; i++) {
                int f  = (i * 256 + tid) * 4;
                int br = f >> 9, col = f & 511;
                *(u64*)(h_lds + br * 516 + col) = hv[i];
            }
        }
        __syncthreads();

        // ---------------- 32 MFMAs ----------------
        f32x4 acc0 = (f32x4){0.f, 0.f, 0.f, 0.f};
        f32x4 acc1 = (f32x4){0.f, 0.f, 0.f, 0.f};
#pragma unroll
        for (int kk = 0; kk < 16; kk++) {
            const __bf16* p0 = h_lds + arow * 516 + kq8 + kk * 32;
            const __bf16* p1 = p0 + 16 * 516;
            bf16x8 a0 = frag_from(*(const u64*)p0, *(const u64*)(p0 + 4));
            bf16x8 a1 = frag_from(*(const u64*)p1, *(const u64*)(p1 + 4));
            acc0 = MFMA16(a0, wreg[kk], acc0);
            acc1 = MFMA16(a1, wreg[kk], acc1);
        }
        {
            int col   = wv * 16 + (lane & 15);
            int rbase = (lane >> 4) * 4;
#pragma unroll
            for (int r = 0; r < 4; r++) {
                g_lds[(rbase + r) * 68 + col]      = acc0[r];
                g_lds[(16 + rbase + r) * 68 + col] = acc1[r];
            }
        }
        __syncthreads();

        // ---------------- per-role epilogue ----------------
        if (role == 1) {
            // pack projection to bf16, store to ring, flag
            const float* gl = g_lds + b * 68 + jp * 2;
            __bf16* xd = xp1r + (size_t)(t & 3) * 65536 + (size_t)b * 2048 + j0;
#pragma unroll
            for (int g = 0; g < 4; g++) {
                f32x2 gv = *(const f32x2*)(gl + g * 16);
                union { __bf16 v2[2]; u32 u; } pu;
                pu.v2[0] = (__bf16)gv[0]; pu.v2[1] = (__bf16)gv[1];
                __hip_atomic_store((u32*)(xd + g * 512), pu.u,
                                   __ATOMIC_RELAXED, SCOPE_AGENT);
            }
            asm volatile("s_waitcnt vmcnt(0)" ::: "memory");
            __syncthreads();
            if (tid == 0)
                __hip_atomic_store(&fX[w * 1024 + t], 1, __ATOMIC_RELAXED, SCOPE_AGENT);
        } else {
            float hf0, hf1;
            {
                u32 x0 = (role == 0) ? xc[0] : xpr[0];
                u32 x1 = (role == 0) ? xc[1] : xpr[1];
                u32 x2 = (role == 0) ? xc[2] : xpr[2];
                u32 x3 = (role == 0) ? xc[3] : xpr[3];
                union { u32 u; __bf16 v2[2]; } xi, xf, xg, xo;
                xi.u = x0; xf.u = x1; xg.u = x2; xo.u = x3;
                const float* gl = g_lds + b * 68 + jp * 2;
                f32x2 gi = *(const f32x2*)(gl);
                f32x2 gf = *(const f32x2*)(gl + 16);
                f32x2 gg = *(const f32x2*)(gl + 32);
                f32x2 go = *(const f32x2*)(gl + 48);

                float i0 = fsigm(gi[0] + (float)xi.v2[0] + bsv[0][0]);
                float f0 = fsigm(gf[0] + (float)xf.v2[0] + bsv[1][0]);
                float g0 = ftanh(gg[0] + (float)xg.v2[0] + bsv[2][0]);
                float o0 = fsigm(go[0] + (float)xo.v2[0] + bsv[3][0]);
                cc0 = f0 * cc0 + i0 * g0;
                hf0 = o0 * ftanh(cc0);

                float i1 = fsigm(gi[1] + (float)xi.v2[1] + bsv[0][1]);
                float f1 = fsigm(gf[1] + (float)xf.v2[1] + bsv[1][1]);
                float g1 = ftanh(gg[1] + (float)xg.v2[1] + bsv[2][1]);
                float o1 = fsigm(go[1] + (float)xo.v2[1] + bsv[3][1]);
                cc1 = f1 * cc1 + i1 * g1;
                hf1 = o1 * ftanh(cc1);
            }
            union { __bf16 v2[2]; u32 u; } hu;
            hu.v2[0] = (__bf16)hf0; hu.v2[1] = (__bf16)hf1;

            // recurrent state store (+ hs0 slot for role 0)
            __hip_atomic_store((u32*)(hbuf + (size_t)((t + 1) & 1) * 16384 +
                                      (size_t)b * 512 + j0),
                               hu.u, __ATOMIC_RELAXED, SCOPE_AGENT);
            if (role == 0)
                __hip_atomic_store((u32*)(hs0s + ((size_t)t * 32 + b) * 512 + j0), hu.u,
                                   __ATOMIC_RELAXED, SCOPE_AGENT);
            asm volatile("s_waitcnt vmcnt(0)" ::: "memory");
            __syncthreads();
            if (tid == 0)
                __hip_atomic_store(&fMy[w * 1024 + t], 1, __ATOMIC_RELAXED, SCOPE_AGENT);

            // non-critical stores overlap flag propagation
            if (role == 2)
                *(f32x2*)(out_f32 + (size_t)b * 524288 + (size_t)t * 512 + j0) =
                    (f32x2){hf0, hf1};
            if (t == 1023) {
                int li = (role == 0) ? 0 : 1;
                *(f32x2*)(hn_out + (size_t)li * 16384 + (size_t)b * 512 + j0) =
                    (f32x2){hf0, hf1};
                *(f32x2*)(cn_out + (size_t)li * 16384 + (size_t)b * 512 + j0) =
                    (f32x2){cc0, cc1};
            }
#pragma unroll
            for (int g = 0; g < 4; g++) xc[g] = xn[g];
        }
    }
}

// ---------------------------------------------------------------------------
extern "C" void kernel_launch(void* const* d_in, const int* in_sizes, int n_in,
                              void* d_out, int out_size, void* d_ws, size_t ws_size,
                              hipStream_t stream) {
    (void)in_sizes; (void)n_in; (void)out_size; (void)ws_size;
    const float* x    = (const float*)d_in[0];  // [32][1024][256] fp32
    const float* Wih0 = (const float*)d_in[1];  // [2048][256] fp32
    const float* b0   = (const float*)d_in[2];  // [2048] fp32
    const float* Whh0 = (const float*)d_in[3];  // [2048][512] fp32
    const float* Wih1 = (const float*)d_in[4];  // [2048][512] fp32
    const float* b1   = (const float*)d_in[5];  // [2048] fp32
    const float* Whh1 = (const float*)d_in[6];  // [2048][512] fp32
    float* dout = (float*)d_out;  // fp32: out(16777216) | h_n(2*16384) | c_n(2*16384)

    char* wsb = (char*)d_ws;
    int*    fL0   = (int*)wsb;                                  // 128 KB
    int*    fX    = (int*)(wsb + (128 << 10));                  // 128 KB
    int*    fL1   = (int*)(wsb + (256 << 10));                  // 128 KB
    __bf16* hbuf0 = (__bf16*)(wsb + (384 << 10));               // 64 KB
    __bf16* hbuf1 = (__bf16*)(wsb + (448 << 10));               // 64 KB
    __bf16* WB0   = (__bf16*)(wsb + (512 << 10));               // 2 MB
    __bf16* WBw1  = (__bf16*)(wsb + (512 << 10) + (2 << 20));   // 2 MB
    __bf16* WBi1  = (__bf16*)(wsb + (512 << 10) + (4 << 20));   // 2 MB
    __bf16* xp1r  = (__bf16*)(wsb + (512 << 10) + (6 << 20));   // 512 KB
    __bf16* hs0s  = (__bf16*)(wsb + (1 << 20) + (7 << 20));     // 32 MB
    __bf16* xpb   = (__bf16*)(wsb + (40 << 20));                // 128 MB

    // zero flags + both h double-buffers (contiguous 512 KB)
    (void)hipMemsetAsync(wsb, 0, 512 << 10, stream);

    pack_w3<<<dim3(1536), dim3(256), 0, stream>>>(Whh0, Whh1, Wih1, WB0, WBw1, WBi1);

    // xp0 = x @ Wih0^T  (K=256, fp32 A, permuted rows)
    gemm_xp<<<dim3(4096), dim3(256), 0, stream>>>(x, Wih0, xpb, 256);

    lstm_pipe3<<<dim3(96), dim3(256), 0, stream>>>(
        xpb, WB0, WBw1, WBi1, b0, b1, hbuf0, hbuf1, hs0s, xp1r,
        dout, dout + 16777216, dout + 16777216 + 32768, fL0, fX, fL1);
}